// Round 2
// baseline (428.895 us; speedup 1.0000x reference)
//
#include <hip/hip_runtime.h>
#include <cmath>

constexpr int kB = 8;
constexpr int kN = 1024;
constexpr int kH = 768;
constexpr float kNeg = 1000000000000.0f;  // same fp32 rounding as reference

// ---------------------------------------------------------------------------
// Kernel 1: outputs = lhs @ w1 + b1 (8192x768 @ 768x128), RoPE -> qw, kw
//           bias    = (lhs @ w2 + b2) / 2, stored transposed biasT[b][e'][n]
// ---------------------------------------------------------------------------
__global__ __launch_bounds__(256) void k1_proj_rope(
    const float* __restrict__ lhs, const float* __restrict__ w1,
    const float* __restrict__ b1, const float* __restrict__ w2,
    const float* __restrict__ b2, float* __restrict__ qw,
    float* __restrict__ kw, float* __restrict__ biasT)
{
  __shared__ float xs[16][kH];  // 48 KB
  const int t = threadIdx.x;
  const int g0 = blockIdx.x * 16;

  const float4* lhs4 = reinterpret_cast<const float4*>(lhs + (size_t)g0 * kH);
  float4* xs4 = reinterpret_cast<float4*>(&xs[0][0]);
#pragma unroll
  for (int p = 0; p < 12; ++p) xs4[t + p * 256] = lhs4[t + p * 256];
  __syncthreads();

  const int c = t & 31;
  const int r2 = t >> 5;
  float acc0[4] = {0.f, 0.f, 0.f, 0.f};
  float acc1[4] = {0.f, 0.f, 0.f, 0.f};
  const float* xr0 = xs[r2];
  const float* xr1 = xs[r2 + 8];
  for (int h = 0; h < kH; h += 4) {
    float x0[4], x1[4];
    *reinterpret_cast<float4*>(x0) = *reinterpret_cast<const float4*>(&xr0[h]);
    *reinterpret_cast<float4*>(x1) = *reinterpret_cast<const float4*>(&xr1[h]);
#pragma unroll
    for (int hh = 0; hh < 4; ++hh) {
      const float4 wv =
          *reinterpret_cast<const float4*>(&w1[(size_t)(h + hh) * 128 + 4 * c]);
      acc0[0] += x0[hh] * wv.x; acc0[1] += x0[hh] * wv.y;
      acc0[2] += x0[hh] * wv.z; acc0[3] += x0[hh] * wv.w;
      acc1[0] += x1[hh] * wv.x; acc1[1] += x1[hh] * wv.y;
      acc1[2] += x1[hh] * wv.z; acc1[3] += x1[hh] * wv.w;
    }
  }
  float bb[4];
  *reinterpret_cast<float4*>(bb) = *reinterpret_cast<const float4*>(&b1[4 * c]);

  const float inv = exp2f(-(float)c * 0.41524101186092f);
#pragma unroll
  for (int rr = 0; rr < 2; ++rr) {
    const float* acc = rr ? acc1 : acc0;
    const int g = g0 + r2 + rr * 8;
    const int n = g & (kN - 1);
    float si, co;
    sincosf((float)n * inv, &si, &co);
    const float oq0 = acc[0] + bb[0], ok0 = acc[1] + bb[1];
    const float oq1 = acc[2] + bb[2], ok1 = acc[3] + bb[3];
    float2 qv = make_float2(oq0 * co - oq1 * si, oq1 * co + oq0 * si);
    float2 kv = make_float2(ok0 * co - ok1 * si, ok1 * co + ok0 * si);
    *reinterpret_cast<float2*>(&qw[(size_t)g * 64 + 2 * c]) = qv;
    *reinterpret_cast<float2*>(&kw[(size_t)g * 64 + 2 * c]) = kv;
  }

  for (int idx = t; idx < 288; idx += 256) {
    const int row = idx / 18, col = idx % 18;
    float s = 0.f;
    for (int h = 0; h < kH; h += 4) {
      const float4 xv = *reinterpret_cast<const float4*>(&xs[row][h]);
      s += xv.x * w2[(size_t)h * 18 + col];
      s += xv.y * w2[(size_t)(h + 1) * 18 + col];
      s += xv.z * w2[(size_t)(h + 2) * 18 + col];
      s += xv.w * w2[(size_t)(h + 3) * 18 + col];
    }
    const int g = g0 + row;
    const int b = g >> 10, n = g & (kN - 1);
    biasT[((size_t)b * 18 + col) * kN + n] = (s + b2[col]) * 0.5f;
  }
}

// ---------------------------------------------------------------------------
// Kernel 2: 64x64 tile. Compute with n = tx+16j (conflict-free b128 dot),
// then one in-LDS transpose so each thread owns 4 rows x 4 CONSECUTIVE n.
// Epilogue stores are global_store_dwordx4, 4x256B contiguous per wave instr.
// ---------------------------------------------------------------------------
__global__ __launch_bounds__(256) void k2_logits(
    const float* __restrict__ qw, const float* __restrict__ kw,
    const float* __restrict__ biasT, const float* __restrict__ mask,
    float* __restrict__ out)
{
  constexpr int LD = 68;  // 16B-aligned rows; dot-loop reads are 2-way (free)
  __shared__ float smem[64 * LD * 2 + 576 * 2 + 128];
  float* qs = smem;                 // 64*68
  float* ks = smem + 64 * LD;       // 64*68
  float* ts = smem;                 // transpose buffer — ALIASES qs
  float* bE = smem + 128 * LD;      // 9*64
  float* bO = bE + 576;             // 9*64
  float* mr_s = bO + 576;           // 64
  float* mc_s = mr_s + 64;          // 64

  const int t = threadIdx.x;
  const int b = blockIdx.z;
  const int m0 = blockIdx.y * 64;
  const int n0 = blockIdx.x * 64;

  const float* qg = qw + ((size_t)b * kN + m0) * 64;
  const float* kg = kw + ((size_t)b * kN + n0) * 64;
#pragma unroll
  for (int p = 0; p < 4; ++p) {
    const int idx = t + p * 256;      // 0..1023
    const int row = idx >> 4;
    const int c4 = (idx & 15) << 2;
    *reinterpret_cast<float4*>(&qs[row * LD + c4]) =
        *reinterpret_cast<const float4*>(&qg[row * 64 + c4]);
    *reinterpret_cast<float4*>(&ks[row * LD + c4]) =
        *reinterpret_cast<const float4*>(&kg[row * 64 + c4]);
  }
  for (int idx = t; idx < 576; idx += 256) {
    const int e = idx >> 6, x = idx & 63;
    bE[idx] = biasT[((size_t)b * 18 + 2 * e) * kN + n0 + x];
    bO[idx] = biasT[((size_t)b * 18 + 2 * e + 1) * kN + m0 + x];
  }
  if (t < 64) mr_s[t] = mask[b * kN + m0 + t];
  else if (t < 128) mc_s[t - 64] = mask[b * kN + n0 + (t - 64)];
  __syncthreads();

  const int tx = t & 15;
  const int ty = t >> 4;
  const int ml = ty << 2;

  float acc[4][4] = {};
  for (int d = 0; d < 64; d += 4) {
    float4 q[4], k[4];
#pragma unroll
    for (int i = 0; i < 4; ++i)
      q[i] = *reinterpret_cast<const float4*>(&qs[(ml + i) * LD + d]);
#pragma unroll
    for (int j = 0; j < 4; ++j)
      k[j] = *reinterpret_cast<const float4*>(&ks[(tx + 16 * j) * LD + d]);
#pragma unroll
    for (int i = 0; i < 4; ++i)
#pragma unroll
      for (int j = 0; j < 4; ++j)
        acc[i][j] += q[i].x * k[j].x + q[i].y * k[j].y +
                     q[i].z * k[j].z + q[i].w * k[j].w;
  }

  // ---- transpose scores through LDS (ts aliases qs; acc is in regs) ----
  __syncthreads();
#pragma unroll
  for (int i = 0; i < 4; ++i)
#pragma unroll
    for (int j = 0; j < 4; ++j)
      ts[(ml + i) * LD + tx + 16 * j] = acc[i][j] * 0.125f;
  __syncthreads();

  // new ownership: rows rb..rb+3, cols cb..cb+3 (consecutive!)
  const int rb = ml;          // 4*(t>>4)
  const int cb = tx << 2;     // 4*(t&15)
  float4 sv[4];
#pragma unroll
  for (int i = 0; i < 4; ++i)
    sv[i] = *reinterpret_cast<const float4*>(&ts[(rb + i) * LD + cb]);

  const float4 mrv = *reinterpret_cast<const float4*>(&mr_s[rb]);
  const float4 mcv = *reinterpret_cast<const float4*>(&mc_s[cb]);
  const float mrA[4] = {mrv.x, mrv.y, mrv.z, mrv.w};
  const float mcA[4] = {mcv.x, mcv.y, mcv.z, mcv.w};

  const size_t obase =
      (size_t)b * 9 * kN * kN + (size_t)(m0 + rb) * kN + (n0 + cb);
  for (int e = 0; e < 9; ++e) {
    const float4 bev = *reinterpret_cast<const float4*>(&bE[e * 64 + cb]);
    const float4 bov = *reinterpret_cast<const float4*>(&bO[e * 64 + rb]);
    const float beA[4] = {bev.x, bev.y, bev.z, bev.w};
    const float boA[4] = {bov.x, bov.y, bov.z, bov.w};
    float* oe = out + obase + (size_t)e * kN * kN;
#pragma unroll
    for (int i = 0; i < 4; ++i) {
      const int m = m0 + rb + i;
      const float* s = reinterpret_cast<const float*>(&sv[i]);
      float4 v4;
      float* v = reinterpret_cast<float*>(&v4);
#pragma unroll
      for (int c = 0; c < 4; ++c) {
        const int n = n0 + cb + c;
        float val = s[c] + beA[c] + boA[i];
        val = val * mrA[i] - kNeg * (1.f - mrA[i]);  // row mask
        val = val * mcA[c] - kNeg * (1.f - mcA[c]);  // col mask
        if (m > n) val -= kNeg;                       // tril(k=-1)
        v[c] = val;
      }
      *reinterpret_cast<float4*>(&oe[(size_t)i * kN]) = v4;
    }
  }
}

extern "C" void kernel_launch(void* const* d_in, const int* in_sizes, int n_in,
                              void* d_out, int out_size, void* d_ws, size_t ws_size,
                              hipStream_t stream) {
  const float* lhs  = (const float*)d_in[0];
  const float* mask = (const float*)d_in[1];
  const float* w1   = (const float*)d_in[2];
  const float* b1   = (const float*)d_in[3];
  const float* w2   = (const float*)d_in[4];
  const float* b2   = (const float*)d_in[5];
  float* out = (float*)d_out;

  float* qw    = (float*)d_ws;                       // 2 MB
  float* kwp   = qw  + (size_t)kB * kN * 64;         // 2 MB
  float* biasT = kwp + (size_t)kB * kN * 64;         // 576 KB

  k1_proj_rope<<<dim3(kB * kN / 16), 256, 0, stream>>>(lhs, w1, b1, w2, b2,
                                                       qw, kwp, biasT);
  k2_logits<<<dim3(kN / 64, kN / 64, kB), 256, 0, stream>>>(qw, kwp, biasT,
                                                            mask, out);
}

// Round 3
// 426.808 us; speedup vs baseline: 1.0049x; 1.0049x over previous
//
#include <hip/hip_runtime.h>
#include <cmath>

constexpr int kB = 8;
constexpr int kN = 1024;
constexpr int kH = 768;
constexpr float kNeg = 1000000000000.0f;  // same fp32 rounding as reference

// ---------------------------------------------------------------------------
// Kernel 1 (rewritten): outputs = lhs @ w1 + b1, RoPE -> qw, kw
//                       biasT[b][e'][n] = ((lhs @ w2 + b2) / 2)^T
// 256 blocks x 512 threads. Block = 32 rows x 128 cols, K=768 in 8 chunks
// of 96. w1 chunk staged in LDS (48 KB, one load per BLOCK, not per wave).
// x chunk in LDS padded to stride 100 (bank-spread: 100 % 32 = 4).
// Thread t: cols 4c..4c+3 (c = t&31), rows rp and rp+16 (rp = t>>5).
// ---------------------------------------------------------------------------
__global__ __launch_bounds__(512) void k1_proj_rope(
    const float* __restrict__ lhs, const float* __restrict__ w1,
    const float* __restrict__ b1, const float* __restrict__ w2,
    const float* __restrict__ b2, float* __restrict__ qw,
    float* __restrict__ kw, float* __restrict__ biasT)
{
  constexpr int CH = 96;    // K-chunk
  constexpr int XP = 100;   // padded x row stride (float4-aligned, %32==4)
  __shared__ float ws1[CH * 128];   // 48 KB
  __shared__ float xs[32 * XP];     // 12.5 KB

  const int t = threadIdx.x;
  const int g0 = blockIdx.x * 32;
  const int c = t & 31;
  const int rp = t >> 5;            // 0..15

  float acc0[4] = {0.f, 0.f, 0.f, 0.f};
  float acc1[4] = {0.f, 0.f, 0.f, 0.f};

  // bias dot assignments: idx = t (always) and t+512 (t<64); 576 = 32 rows x 18
  const int row0 = t / 18, col0 = t % 18;
  const int row1 = (t + 512) / 18, col1 = (t + 512) % 18;
  float sb0 = 0.f, sb1 = 0.f;

  for (int ch = 0; ch < 8; ++ch) {
    // stage w1 chunk: rows [ch*96, ch*96+96) x 128 cols = 3072 float4
    const float4* w1g = reinterpret_cast<const float4*>(w1 + (size_t)ch * CH * 128);
    float4* ws4 = reinterpret_cast<float4*>(ws1);
#pragma unroll
    for (int p = 0; p < 6; ++p) ws4[t + p * 512] = w1g[t + p * 512];
    // stage x chunk: 32 rows x 96 cols = 768 float4 (24 per row)
#pragma unroll
    for (int p = 0; p < 2; ++p) {
      const int idx = t + p * 512;
      if (idx < 768) {
        const int row = idx / 24, c4 = idx % 24;
        *reinterpret_cast<float4*>(&xs[row * XP + c4 * 4]) =
            *reinterpret_cast<const float4*>(
                &lhs[(size_t)(g0 + row) * kH + ch * CH + c4 * 4]);
      }
    }
    __syncthreads();

    const float* xr0 = &xs[rp * XP];
    const float* xr1 = &xs[(rp + 16) * XP];
    for (int h = 0; h < CH; h += 4) {
      float x0[4], x1[4];
      *reinterpret_cast<float4*>(x0) = *reinterpret_cast<const float4*>(&xr0[h]);
      *reinterpret_cast<float4*>(x1) = *reinterpret_cast<const float4*>(&xr1[h]);
#pragma unroll
      for (int hh = 0; hh < 4; ++hh) {
        const float4 wv = *reinterpret_cast<const float4*>(&ws1[(h + hh) * 128 + 4 * c]);
        acc0[0] += x0[hh] * wv.x; acc0[1] += x0[hh] * wv.y;
        acc0[2] += x0[hh] * wv.z; acc0[3] += x0[hh] * wv.w;
        acc1[0] += x1[hh] * wv.x; acc1[1] += x1[hh] * wv.y;
        acc1[2] += x1[hh] * wv.z; acc1[3] += x1[hh] * wv.w;
      }
    }

    // bias partial dots over this chunk (xs rows padded -> conflict-free)
    {
      const int hb = ch * CH;
      const float* xr = &xs[row0 * XP];
      for (int h = 0; h < CH; h += 4) {
        const float4 xv = *reinterpret_cast<const float4*>(&xr[h]);
        sb0 += xv.x * w2[(size_t)(hb + h) * 18 + col0];
        sb0 += xv.y * w2[(size_t)(hb + h + 1) * 18 + col0];
        sb0 += xv.z * w2[(size_t)(hb + h + 2) * 18 + col0];
        sb0 += xv.w * w2[(size_t)(hb + h + 3) * 18 + col0];
      }
      if (t < 64) {
        const float* xr1b = &xs[row1 * XP];
        for (int h = 0; h < CH; h += 4) {
          const float4 xv = *reinterpret_cast<const float4*>(&xr1b[h]);
          sb1 += xv.x * w2[(size_t)(hb + h) * 18 + col1];
          sb1 += xv.y * w2[(size_t)(hb + h + 1) * 18 + col1];
          sb1 += xv.z * w2[(size_t)(hb + h + 2) * 18 + col1];
          sb1 += xv.w * w2[(size_t)(hb + h + 3) * 18 + col1];
        }
      }
    }
    __syncthreads();
  }

  // RoPE + store q/k. cols 4c,4c+2 -> q pair (2c,2c+1); 4c+1,4c+3 -> k pair.
  float bb[4];
  *reinterpret_cast<float4*>(bb) = *reinterpret_cast<const float4*>(&b1[4 * c]);
  const float inv = exp2f(-(float)c * 0.41524101186092f);  // 10000^(-c/32)
#pragma unroll
  for (int rr = 0; rr < 2; ++rr) {
    const float* acc = rr ? acc1 : acc0;
    const int g = g0 + rp + rr * 16;
    const int n = g & (kN - 1);
    float si, co;
    sincosf((float)n * inv, &si, &co);
    const float oq0 = acc[0] + bb[0], ok0 = acc[1] + bb[1];
    const float oq1 = acc[2] + bb[2], ok1 = acc[3] + bb[3];
    float2 qv = make_float2(oq0 * co - oq1 * si, oq1 * co + oq0 * si);
    float2 kv = make_float2(ok0 * co - ok1 * si, ok1 * co + ok0 * si);
    *reinterpret_cast<float2*>(&qw[(size_t)g * 64 + 2 * c]) = qv;
    *reinterpret_cast<float2*>(&kw[(size_t)g * 64 + 2 * c]) = kv;
  }

  // bias writes (transposed layout biasT[b][18][n])
  {
    const int g = g0 + row0;
    const int b = g >> 10, n = g & (kN - 1);
    biasT[((size_t)b * 18 + col0) * kN + n] = (sb0 + b2[col0]) * 0.5f;
  }
  if (t < 64) {
    const int g = g0 + row1;
    const int b = g >> 10, n = g & (kN - 1);
    biasT[((size_t)b * 18 + col1) * kN + n] = (sb1 + b2[col1]) * 0.5f;
  }
}

// ---------------------------------------------------------------------------
// Kernel 2 (UNCHANGED from R2): 64x64 tile, conflict-free b128 dot, in-LDS
// transpose, dwordx4 epilogue stores.
// ---------------------------------------------------------------------------
__global__ __launch_bounds__(256) void k2_logits(
    const float* __restrict__ qw, const float* __restrict__ kw,
    const float* __restrict__ biasT, const float* __restrict__ mask,
    float* __restrict__ out)
{
  constexpr int LD = 68;
  __shared__ float smem[64 * LD * 2 + 576 * 2 + 128];
  float* qs = smem;
  float* ks = smem + 64 * LD;
  float* ts = smem;  // aliases qs
  float* bE = smem + 128 * LD;
  float* bO = bE + 576;
  float* mr_s = bO + 576;
  float* mc_s = mr_s + 64;

  const int t = threadIdx.x;
  const int b = blockIdx.z;
  const int m0 = blockIdx.y * 64;
  const int n0 = blockIdx.x * 64;

  const float* qg = qw + ((size_t)b * kN + m0) * 64;
  const float* kg = kw + ((size_t)b * kN + n0) * 64;
#pragma unroll
  for (int p = 0; p < 4; ++p) {
    const int idx = t + p * 256;
    const int row = idx >> 4;
    const int c4 = (idx & 15) << 2;
    *reinterpret_cast<float4*>(&qs[row * LD + c4]) =
        *reinterpret_cast<const float4*>(&qg[row * 64 + c4]);
    *reinterpret_cast<float4*>(&ks[row * LD + c4]) =
        *reinterpret_cast<const float4*>(&kg[row * 64 + c4]);
  }
  for (int idx = t; idx < 576; idx += 256) {
    const int e = idx >> 6, x = idx & 63;
    bE[idx] = biasT[((size_t)b * 18 + 2 * e) * kN + n0 + x];
    bO[idx] = biasT[((size_t)b * 18 + 2 * e + 1) * kN + m0 + x];
  }
  if (t < 64) mr_s[t] = mask[b * kN + m0 + t];
  else if (t < 128) mc_s[t - 64] = mask[b * kN + n0 + (t - 64)];
  __syncthreads();

  const int tx = t & 15;
  const int ty = t >> 4;
  const int ml = ty << 2;

  float acc[4][4] = {};
  for (int d = 0; d < 64; d += 4) {
    float4 q[4], k[4];
#pragma unroll
    for (int i = 0; i < 4; ++i)
      q[i] = *reinterpret_cast<const float4*>(&qs[(ml + i) * LD + d]);
#pragma unroll
    for (int j = 0; j < 4; ++j)
      k[j] = *reinterpret_cast<const float4*>(&ks[(tx + 16 * j) * LD + d]);
#pragma unroll
    for (int i = 0; i < 4; ++i)
#pragma unroll
      for (int j = 0; j < 4; ++j)
        acc[i][j] += q[i].x * k[j].x + q[i].y * k[j].y +
                     q[i].z * k[j].z + q[i].w * k[j].w;
  }

  __syncthreads();
#pragma unroll
  for (int i = 0; i < 4; ++i)
#pragma unroll
    for (int j = 0; j < 4; ++j)
      ts[(ml + i) * LD + tx + 16 * j] = acc[i][j] * 0.125f;
  __syncthreads();

  const int rb = ml;
  const int cb = tx << 2;
  float4 sv[4];
#pragma unroll
  for (int i = 0; i < 4; ++i)
    sv[i] = *reinterpret_cast<const float4*>(&ts[(rb + i) * LD + cb]);

  const float4 mrv = *reinterpret_cast<const float4*>(&mr_s[rb]);
  const float4 mcv = *reinterpret_cast<const float4*>(&mc_s[cb]);
  const float mrA[4] = {mrv.x, mrv.y, mrv.z, mrv.w};
  const float mcA[4] = {mcv.x, mcv.y, mcv.z, mcv.w};

  const size_t obase =
      (size_t)b * 9 * kN * kN + (size_t)(m0 + rb) * kN + (n0 + cb);
  for (int e = 0; e < 9; ++e) {
    const float4 bev = *reinterpret_cast<const float4*>(&bE[e * 64 + cb]);
    const float4 bov = *reinterpret_cast<const float4*>(&bO[e * 64 + rb]);
    const float beA[4] = {bev.x, bev.y, bev.z, bev.w};
    const float boA[4] = {bov.x, bov.y, bov.z, bov.w};
    float* oe = out + obase + (size_t)e * kN * kN;
#pragma unroll
    for (int i = 0; i < 4; ++i) {
      const int m = m0 + rb + i;
      const float* s = reinterpret_cast<const float*>(&sv[i]);
      float4 v4;
      float* v = reinterpret_cast<float*>(&v4);
#pragma unroll
      for (int cc = 0; cc < 4; ++cc) {
        const int n = n0 + cb + cc;
        float val = s[cc] + beA[cc] + boA[i];
        val = val * mrA[i] - kNeg * (1.f - mrA[i]);
        val = val * mcA[cc] - kNeg * (1.f - mcA[cc]);
        if (m > n) val -= kNeg;
        v[cc] = val;
      }
      *reinterpret_cast<float4*>(&oe[(size_t)i * kN]) = v4;
    }
  }
}

extern "C" void kernel_launch(void* const* d_in, const int* in_sizes, int n_in,
                              void* d_out, int out_size, void* d_ws, size_t ws_size,
                              hipStream_t stream) {
  const float* lhs  = (const float*)d_in[0];
  const float* mask = (const float*)d_in[1];
  const float* w1   = (const float*)d_in[2];
  const float* b1   = (const float*)d_in[3];
  const float* w2   = (const float*)d_in[4];
  const float* b2   = (const float*)d_in[5];
  float* out = (float*)d_out;

  float* qw    = (float*)d_ws;                       // 2 MB
  float* kwp   = qw  + (size_t)kB * kN * 64;         // 2 MB
  float* biasT = kwp + (size_t)kB * kN * 64;         // 576 KB

  k1_proj_rope<<<dim3(kB * kN / 32), 512, 0, stream>>>(lhs, w1, b1, w2, b2,
                                                       qw, kwp, biasT);
  k2_logits<<<dim3(kN / 64, kN / 64, kB), 256, 0, stream>>>(qw, kwp, biasT,
                                                            mask, out);
}

// Round 4
// 425.770 us; speedup vs baseline: 1.0073x; 1.0024x over previous
//
#include <hip/hip_runtime.h>
#include <hip/hip_bf16.h>
#include <cmath>

constexpr int kB = 8;
constexpr int kN = 1024;
constexpr int kH = 768;
constexpr float kNeg = 1000000000000.0f;  // same fp32 rounding as reference

typedef __attribute__((ext_vector_type(8))) short s8v;   // 8 bf16 = 4 VGPRs
typedef __attribute__((ext_vector_type(4))) float f4v;   // MFMA acc

// ---------------------------------------------------------------------------
// Kernel 1: outputs = lhs @ w1 + b1, RoPE -> qw, kw  (NOW STORED AS BF16)
//           biasT[b][e'][n] = ((lhs @ w2 + b2) / 2)^T   (fp32)
// Structure unchanged from R3 (512 thr, w1 chunk in LDS) — k1 addressed next.
// ---------------------------------------------------------------------------
__global__ __launch_bounds__(512) void k1_proj_rope(
    const float* __restrict__ lhs, const float* __restrict__ w1,
    const float* __restrict__ b1, const float* __restrict__ w2,
    const float* __restrict__ b2, __hip_bfloat16* __restrict__ qw,
    __hip_bfloat16* __restrict__ kw, float* __restrict__ biasT)
{
  constexpr int CH = 96;
  constexpr int XP = 100;
  __shared__ float ws1[CH * 128];
  __shared__ float xs[32 * XP];

  const int t = threadIdx.x;
  const int g0 = blockIdx.x * 32;
  const int c = t & 31;
  const int rp = t >> 5;

  float acc0[4] = {0.f, 0.f, 0.f, 0.f};
  float acc1[4] = {0.f, 0.f, 0.f, 0.f};

  const int row0 = t / 18, col0 = t % 18;
  const int row1 = (t + 512) / 18, col1 = (t + 512) % 18;
  float sb0 = 0.f, sb1 = 0.f;

  for (int ch = 0; ch < 8; ++ch) {
    const float4* w1g = reinterpret_cast<const float4*>(w1 + (size_t)ch * CH * 128);
    float4* ws4 = reinterpret_cast<float4*>(ws1);
#pragma unroll
    for (int p = 0; p < 6; ++p) ws4[t + p * 512] = w1g[t + p * 512];
#pragma unroll
    for (int p = 0; p < 2; ++p) {
      const int idx = t + p * 512;
      if (idx < 768) {
        const int row = idx / 24, c4 = idx % 24;
        *reinterpret_cast<float4*>(&xs[row * XP + c4 * 4]) =
            *reinterpret_cast<const float4*>(
                &lhs[(size_t)(g0 + row) * kH + ch * CH + c4 * 4]);
      }
    }
    __syncthreads();

    const float* xr0 = &xs[rp * XP];
    const float* xr1 = &xs[(rp + 16) * XP];
    for (int h = 0; h < CH; h += 4) {
      float x0[4], x1[4];
      *reinterpret_cast<float4*>(x0) = *reinterpret_cast<const float4*>(&xr0[h]);
      *reinterpret_cast<float4*>(x1) = *reinterpret_cast<const float4*>(&xr1[h]);
#pragma unroll
      for (int hh = 0; hh < 4; ++hh) {
        const float4 wv = *reinterpret_cast<const float4*>(&ws1[(h + hh) * 128 + 4 * c]);
        acc0[0] += x0[hh] * wv.x; acc0[1] += x0[hh] * wv.y;
        acc0[2] += x0[hh] * wv.z; acc0[3] += x0[hh] * wv.w;
        acc1[0] += x1[hh] * wv.x; acc1[1] += x1[hh] * wv.y;
        acc1[2] += x1[hh] * wv.z; acc1[3] += x1[hh] * wv.w;
      }
    }

    {
      const int hb = ch * CH;
      const float* xr = &xs[row0 * XP];
      for (int h = 0; h < CH; h += 4) {
        const float4 xv = *reinterpret_cast<const float4*>(&xr[h]);
        sb0 += xv.x * w2[(size_t)(hb + h) * 18 + col0];
        sb0 += xv.y * w2[(size_t)(hb + h + 1) * 18 + col0];
        sb0 += xv.z * w2[(size_t)(hb + h + 2) * 18 + col0];
        sb0 += xv.w * w2[(size_t)(hb + h + 3) * 18 + col0];
      }
      if (t < 64) {
        const float* xr1b = &xs[row1 * XP];
        for (int h = 0; h < CH; h += 4) {
          const float4 xv = *reinterpret_cast<const float4*>(&xr1b[h]);
          sb1 += xv.x * w2[(size_t)(hb + h) * 18 + col1];
          sb1 += xv.y * w2[(size_t)(hb + h + 1) * 18 + col1];
          sb1 += xv.z * w2[(size_t)(hb + h + 2) * 18 + col1];
          sb1 += xv.w * w2[(size_t)(hb + h + 3) * 18 + col1];
        }
      }
    }
    __syncthreads();
  }

  float bb[4];
  *reinterpret_cast<float4*>(bb) = *reinterpret_cast<const float4*>(&b1[4 * c]);
  const float inv = exp2f(-(float)c * 0.41524101186092f);  // 10000^(-c/32)
#pragma unroll
  for (int rr = 0; rr < 2; ++rr) {
    const float* acc = rr ? acc1 : acc0;
    const int g = g0 + rp + rr * 16;
    const int n = g & (kN - 1);
    float si, co;
    sincosf((float)n * inv, &si, &co);
    const float oq0 = acc[0] + bb[0], ok0 = acc[1] + bb[1];
    const float oq1 = acc[2] + bb[2], ok1 = acc[3] + bb[3];
    __hip_bfloat162 qv, kv;
    qv.x = __float2bfloat16(oq0 * co - oq1 * si);
    qv.y = __float2bfloat16(oq1 * co + oq0 * si);
    kv.x = __float2bfloat16(ok0 * co - ok1 * si);
    kv.y = __float2bfloat16(ok1 * co + ok0 * si);
    *reinterpret_cast<__hip_bfloat162*>(&qw[(size_t)g * 64 + 2 * c]) = qv;
    *reinterpret_cast<__hip_bfloat162*>(&kw[(size_t)g * 64 + 2 * c]) = kv;
  }

  {
    const int g = g0 + row0;
    const int b = g >> 10, n = g & (kN - 1);
    biasT[((size_t)b * 18 + col0) * kN + n] = (sb0 + b2[col0]) * 0.5f;
  }
  if (t < 64) {
    const int g = g0 + row1;
    const int b = g >> 10, n = g & (kN - 1);
    biasT[((size_t)b * 18 + col1) * kN + n] = (sb1 + b2[col1]) * 0.5f;
  }
}

// ---------------------------------------------------------------------------
// Kernel 2 (MFMA rewrite, ZERO LDS): block = 64m x 64n, 4 waves; each wave
// computes a 16x64 strip via 8x mfma_f32_16x16x32_bf16. Fragments loaded
// directly from global (qw/kw bf16, row-major = A/B operand layout; 2 MB
// total, L2/L3-resident). Epilogue in fp32 straight from C/D layout:
// col = lane&15, row = quad*4+reg -> each store = 4 x 64B full lines.
// ---------------------------------------------------------------------------
__global__ __launch_bounds__(256) void k2_logits(
    const __hip_bfloat16* __restrict__ qw, const __hip_bfloat16* __restrict__ kw,
    const float* __restrict__ biasT, const float* __restrict__ mask,
    float* __restrict__ out)
{
  const int t = threadIdx.x;
  const int lane = t & 63;
  const int wid = t >> 6;          // wave 0..3 -> m-strip
  const int tx = lane & 15;
  const int quad = lane >> 4;
  const int b = blockIdx.z;
  const int m0 = blockIdx.y * 64;
  const int n0 = blockIdx.x * 64;
  const int ms = m0 + wid * 16;

  // A fragment: lane reads qw[ms+tx][quad*8 .. +8)  (16 B, coalesced)
  const short* qp =
      reinterpret_cast<const short*>(qw) + ((size_t)b * kN + ms + tx) * 64;
  const short* kp =
      reinterpret_cast<const short*>(kw) + ((size_t)b * kN + n0 + tx) * 64;

  const s8v a0 = *reinterpret_cast<const s8v*>(qp + quad * 8);
  const s8v a1 = *reinterpret_cast<const s8v*>(qp + 32 + quad * 8);

  f4v acc[4] = {f4v{0,0,0,0}, f4v{0,0,0,0}, f4v{0,0,0,0}, f4v{0,0,0,0}};
#pragma unroll
  for (int j = 0; j < 4; ++j) {
    const short* kj = kp + (size_t)j * 16 * 64;
    const s8v b0 = *reinterpret_cast<const s8v*>(kj + quad * 8);
    const s8v b1 = *reinterpret_cast<const s8v*>(kj + 32 + quad * 8);
    acc[j] = __builtin_amdgcn_mfma_f32_16x16x32_bf16(a0, b0, acc[j], 0, 0, 0);
    acc[j] = __builtin_amdgcn_mfma_f32_16x16x32_bf16(a1, b1, acc[j], 0, 0, 0);
  }

  // masks (fp32, exact reference arithmetic)
  const float* mrow = mask + (size_t)b * kN;
  float mc[4], mr[4];
#pragma unroll
  for (int j = 0; j < 4; ++j) mc[j] = mrow[n0 + 16 * j + tx];
#pragma unroll
  for (int r = 0; r < 4; ++r) mr[r] = mrow[ms + quad * 4 + r];

  const size_t obb = (size_t)b * 9 * kN * kN;
  for (int e = 0; e < 9; ++e) {
    const float* bEr = biasT + ((size_t)b * 18 + 2 * e) * kN;
    const float* bOr = biasT + ((size_t)b * 18 + 2 * e + 1) * kN;
    float be[4], bo[4];
#pragma unroll
    for (int j = 0; j < 4; ++j) be[j] = bEr[n0 + 16 * j + tx];
#pragma unroll
    for (int r = 0; r < 4; ++r) bo[r] = bOr[ms + quad * 4 + r];

    float* oe = out + obb + (size_t)e * kN * kN;
#pragma unroll
    for (int r = 0; r < 4; ++r) {
      const int m = ms + quad * 4 + r;
      float* orow = oe + (size_t)m * kN;
#pragma unroll
      for (int j = 0; j < 4; ++j) {
        const int n = n0 + 16 * j + tx;
        float v = acc[j][r] * 0.125f + be[j] + bo[r];
        v = v * mr[r] - kNeg * (1.f - mr[r]);   // row mask
        v = v * mc[j] - kNeg * (1.f - mc[j]);   // col mask
        if (m > n) v -= kNeg;                    // tril(k=-1)
        orow[n] = v;
      }
    }
  }
}

extern "C" void kernel_launch(void* const* d_in, const int* in_sizes, int n_in,
                              void* d_out, int out_size, void* d_ws, size_t ws_size,
                              hipStream_t stream) {
  const float* lhs  = (const float*)d_in[0];
  const float* mask = (const float*)d_in[1];
  const float* w1   = (const float*)d_in[2];
  const float* b1   = (const float*)d_in[3];
  const float* w2   = (const float*)d_in[4];
  const float* b2   = (const float*)d_in[5];
  float* out = (float*)d_out;

  __hip_bfloat16* qw  = (__hip_bfloat16*)d_ws;                 // 1 MB
  __hip_bfloat16* kwp = qw + (size_t)kB * kN * 64;             // 1 MB
  float* biasT = (float*)(kwp + (size_t)kB * kN * 64);         // 576 KB fp32

  k1_proj_rope<<<dim3(kB * kN / 32), 512, 0, stream>>>(lhs, w1, b1, w2, b2,
                                                       qw, kwp, biasT);
  k2_logits<<<dim3(kN / 64, kN / 64, kB), 256, 0, stream>>>(qw, kwp, biasT,
                                                            mask, out);
}